// Round 3
// baseline (1488.123 us; speedup 1.0000x reference)
//
#include <hip/hip_runtime.h>

// ---------------------------------------------------------------------------
// 2-layer hetero GraphSAGE, bipartite user<->item, H=256. Round 3.
// Change vs round 2: MFMA GEMM v2 — both A and W staged into LDS per K-chunk
// in fragment-ready layout (conflict-free ds_read_b128), 64-row tiles, 2x2
// wave grid, register prefetch of next chunk overlapping MFMA. Round-2's GEMM
// read B-frags from L2 per-MFMA -> 4% MfmaUtil, latency-bound.
// Also: F=256 aggregation uses 16B/lane (half-wave per row, 8-deep unroll).
// ---------------------------------------------------------------------------

typedef unsigned short u16;
typedef unsigned int u32;
typedef short bf16x8 __attribute__((ext_vector_type(8)));   // 8 bf16 (4 VGPRs)
typedef float f32x4 __attribute__((ext_vector_type(4)));    // MFMA acc

constexpr int HDIM = 256;

// ---------------- bf16 helpers ----------------

__device__ __forceinline__ float lo2f(u32 v) { union { u32 i; float f; } x; x.i = v << 16; return x.f; }
__device__ __forceinline__ float hi2f(u32 v) { union { u32 i; float f; } x; x.i = v & 0xffff0000u; return x.f; }
__device__ __forceinline__ float bf2f(u16 v) { union { u32 i; float f; } x; x.i = ((u32)v) << 16; return x.f; }
__device__ __forceinline__ u16 f2bf(float f) {  // RNE
    union { float f; u32 i; } x; x.f = f;
    return (u16)((x.i + 0x7fffu + ((x.i >> 16) & 1u)) >> 16);
}
__device__ __forceinline__ u32 pack2(float a, float b) {
    return (u32)f2bf(a) | ((u32)f2bf(b) << 16);
}

// ---------------- CSR build ----------------

__global__ void hist_kernel(const int* __restrict__ dst, int n, int* __restrict__ cnt) {
    int i = blockIdx.x * 256 + threadIdx.x;
    if (i < n) atomicAdd(&cnt[dst[i]], 1);
}

__global__ void block_reduce_kernel(const int* __restrict__ cnt, int n, int* __restrict__ sums) {
    __shared__ int sdata[256];
    int b = blockIdx.x, t = threadIdx.x;
    int v = 0;
#pragma unroll
    for (int j = 0; j < 4; j++) {
        int idx = b * 1024 + j * 256 + t;
        if (idx < n) v += cnt[idx];
    }
    sdata[t] = v;
    __syncthreads();
    for (int s = 128; s > 0; s >>= 1) {
        if (t < s) sdata[t] += sdata[t + s];
        __syncthreads();
    }
    if (t == 0) sums[b] = sdata[0];
}

__global__ void scan_sums_kernel(const int* __restrict__ sums, int* __restrict__ offs, int B) {
    if (blockIdx.x == 0 && threadIdx.x == 0) {
        int a = 0;
        for (int i = 0; i < B; i++) { offs[i] = a; a += sums[i]; }
    }
}

__global__ void block_scan_write_kernel(const int* cnt, int n, const int* __restrict__ offs,
                                        int* __restrict__ rp, int* cursor, int total) {
    __shared__ int sdata[1024];
    int b = blockIdx.x, t = threadIdx.x;
    int idx = b * 1024 + t;
    int v = (idx < n) ? cnt[idx] : 0;
    sdata[t] = v;
    __syncthreads();
    for (int s = 1; s < 1024; s <<= 1) {
        int x = (t >= s) ? sdata[t - s] : 0;
        __syncthreads();
        sdata[t] += x;
        __syncthreads();
    }
    if (idx < n) {
        int excl = sdata[t] - v + offs[b];
        rp[idx] = excl;
        cursor[idx] = excl;
    }
    if (b == 0 && t == 0) rp[n] = total;
}

__global__ void fill_kernel(const int* __restrict__ src, const int* __restrict__ dst, int n,
                            int* cursor, int* __restrict__ col) {
    int i = blockIdx.x * 256 + threadIdx.x;
    if (i < n) {
        int p = atomicAdd(&cursor[dst[i]], 1);
        col[p] = src[i];
    }
}

// ---------------- fp32 -> bf16 convert ----------------

__global__ void f32_to_bf16_kernel(const float* __restrict__ in, u16* __restrict__ out, int n4) {
    int i = blockIdx.x * 256 + threadIdx.x;
    if (i < n4) {
        float4 v = ((const float4*)in)[i];
        ((uint2*)out)[i] = make_uint2(pack2(v.x, v.y), pack2(v.z, v.w));
    }
}

// ---------------- mean aggregation, F=128/64: 1 wave per dst row ----------------

template <int F>
__global__ __launch_bounds__(256) void agg_mean(const u16* __restrict__ src,
                                                const int* __restrict__ rp,
                                                const int* __restrict__ col,
                                                u16* __restrict__ out, int n_dst) {
    constexpr int VE = F / 64;  // bf16 per lane: 2 / 1
    const int lane = threadIdx.x & 63;
    const int d = blockIdx.x * 4 + (threadIdx.x >> 6);
    if (d >= n_dst) return;
    const int e0 = rp[d], e1 = rp[d + 1];
    float a0 = 0.f, a1 = 0.f;
    const size_t lo = (size_t)lane * VE;

    auto add = [&](int c) {
        const u16* p = src + (size_t)c * F + lo;
        if (VE == 2) {
            u32 v = *(const u32*)p;
            a0 += lo2f(v); a1 += hi2f(v);
        } else {
            a0 += bf2f(*p);
        }
    };

    int e = e0;
    for (; e + 4 <= e1; e += 4) {
        int c0 = col[e], c1 = col[e + 1], c2 = col[e + 2], c3 = col[e + 3];
        add(c0); add(c1); add(c2); add(c3);
    }
    for (; e < e1; e++) add(col[e]);

    int deg = e1 - e0;
    float inv = (deg > 0) ? 1.f / (float)deg : 0.f;
    a0 *= inv; a1 *= inv;

    u16* q = out + (size_t)d * F + lo;
    if (VE == 2) ((u32*)q)[0] = pack2(a0, a1);
    else         *q = f2bf(a0);
}

// ---------------- mean aggregation, F=256: half-wave (32 lanes) per row ----------------
// 16B/lane loads, 8 edges in flight (128B/lane outstanding).

__global__ __launch_bounds__(256) void agg_mean_256(const u16* __restrict__ src,
                                                    const int* __restrict__ rp,
                                                    const int* __restrict__ col,
                                                    u16* __restrict__ out, int n_dst) {
    const int lane = threadIdx.x & 31;
    const int d = blockIdx.x * 8 + (threadIdx.x >> 5);
    if (d >= n_dst) return;
    const int e0 = rp[d], e1 = rp[d + 1];
    float a0 = 0, a1 = 0, a2 = 0, a3 = 0, a4 = 0, a5 = 0, a6 = 0, a7 = 0;
    const size_t lo = (size_t)lane * 8;

    auto addv = [&](uint4 v) {
        a0 += lo2f(v.x); a1 += hi2f(v.x); a2 += lo2f(v.y); a3 += hi2f(v.y);
        a4 += lo2f(v.z); a5 += hi2f(v.z); a6 += lo2f(v.w); a7 += hi2f(v.w);
    };

    int e = e0;
    for (; e + 8 <= e1; e += 8) {
        uint4 v0 = *(const uint4*)(src + (size_t)col[e]     * 256 + lo);
        uint4 v1 = *(const uint4*)(src + (size_t)col[e + 1] * 256 + lo);
        uint4 v2 = *(const uint4*)(src + (size_t)col[e + 2] * 256 + lo);
        uint4 v3 = *(const uint4*)(src + (size_t)col[e + 3] * 256 + lo);
        uint4 v4 = *(const uint4*)(src + (size_t)col[e + 4] * 256 + lo);
        uint4 v5 = *(const uint4*)(src + (size_t)col[e + 5] * 256 + lo);
        uint4 v6 = *(const uint4*)(src + (size_t)col[e + 6] * 256 + lo);
        uint4 v7 = *(const uint4*)(src + (size_t)col[e + 7] * 256 + lo);
        addv(v0); addv(v1); addv(v2); addv(v3); addv(v4); addv(v5); addv(v6); addv(v7);
    }
    for (; e < e1; e++) addv(*(const uint4*)(src + (size_t)col[e] * 256 + lo));

    int deg = e1 - e0;
    float inv = (deg > 0) ? 1.f / (float)deg : 0.f;
    uint4 o;
    o.x = pack2(a0 * inv, a1 * inv);
    o.y = pack2(a2 * inv, a3 * inv);
    o.z = pack2(a4 * inv, a5 * inv);
    o.w = pack2(a6 * inv, a7 * inv);
    *(uint4*)(out + (size_t)d * 256 + lo) = o;
}

// ---------------- MFMA GEMM v2 ----------------
// out[Mx256] = [A | X] (M x KA+KB) @ [WA | WB]^T + bias.
// Block: 256 thr = 4 waves (2x2: wr = M half, wc = N half). M-tile 64, KC=64.
// LDS fragment-ready: chunk g = 64 lanes x 16B; lane l of A-group (mt,s) holds
// A[row0+mt*16+(l&15)][kc0+s*32+(l>>4)*8 +0..7]; B-group (nt,s) likewise from
// W rows. ds_read_b128 at lane-stride 16B = conflict-free.

template <int KA, int KB, bool RELU, bool OUT_BF16>
__global__ __launch_bounds__(256, 3) void gemm2(const u16* __restrict__ A,
                                                const u16* __restrict__ X,
                                                const u16* __restrict__ WA,
                                                const u16* __restrict__ WB,
                                                const float* __restrict__ bias,
                                                float* __restrict__ outF,
                                                u16* __restrict__ outB, int M) {
    constexpr int KT = KA + KB;
    constexpr int NCH = KT / 64;
    __shared__ __align__(16) u16 lds[8 * 64 * 8 + 32 * 64 * 8];  // A 8KB + B 32KB
    u16* Ablk = lds;
    u16* Bblk = lds + 8 * 64 * 8;

    const int tid = threadIdx.x;
    const int row0 = blockIdx.x * 64;
    const int lane = tid & 63;
    const int wid = tid >> 6;
    const int wr = wid & 1, wc = wid >> 1;
    const int ml = lane & 15, ql = lane >> 4;

    // staging: this thread's lane-part is fixed (l = lane); groups g = wid + 4j.
    const int srow = ml;            // row-within-16 for A groups
    const int skof = ql * 8;        // k offset within 64-k chunk... (s adds 32)

    uint4 ra[2], rb[8];
    auto stage_load = [&](int kc0) {
        const u16* SA; int sas, kofA;
        if (kc0 < KA) { SA = A; sas = KA; kofA = kc0; }
        else          { SA = X; sas = KB; kofA = kc0 - KA; }
        const u16* SW; int sws;
        if (kc0 < KA) { SW = WA; sws = KA; }
        else          { SW = WB; sws = KB; }
#pragma unroll
        for (int j = 0; j < 2; j++) {
            int g = wid + 4 * j;               // 0..7
            int mt = g >> 1, s = g & 1;
            int r = row0 + mt * 16 + srow;
            r = (r < M) ? r : (M - 1);
            ra[j] = *(const uint4*)(SA + (size_t)r * sas + kofA + s * 32 + skof);
        }
#pragma unroll
        for (int j = 0; j < 8; j++) {
            int g = wid + 4 * j;               // 0..31
            int nt = g >> 1, s = g & 1;
            int n = nt * 16 + srow;
            rb[j] = *(const uint4*)(SW + (size_t)n * sws + kofA + s * 32 + skof);
        }
    };
    auto stage_store = [&]() {
#pragma unroll
        for (int j = 0; j < 2; j++)
            *(uint4*)(Ablk + (size_t)(tid + 256 * j) * 8) = ra[j];
#pragma unroll
        for (int j = 0; j < 8; j++)
            *(uint4*)(Bblk + (size_t)(tid + 256 * j) * 8) = rb[j];
    };

    f32x4 acc[2][8];
#pragma unroll
    for (int i = 0; i < 2; i++)
#pragma unroll
        for (int j = 0; j < 8; j++) acc[i][j] = {0.f, 0.f, 0.f, 0.f};

    stage_load(0);
    for (int ch = 0; ch < NCH; ch++) {
        __syncthreads();          // prior chunk's reads complete
        stage_store();
        __syncthreads();
        if (ch + 1 < NCH) stage_load((ch + 1) * 64);  // overlap with MFMAs below
#pragma unroll
        for (int s = 0; s < 2; s++) {
            bf16x8 av[2];
#pragma unroll
            for (int m = 0; m < 2; m++)
                av[m] = *(const bf16x8*)(Ablk + (size_t)((((wr * 2 + m) * 2 + s) * 64) + lane) * 8);
            bf16x8 bv[8];
#pragma unroll
            for (int t = 0; t < 8; t++) {
                int nt = wc * 8 + t;
                bv[t] = *(const bf16x8*)(Bblk + (size_t)(((nt * 2 + s) * 64) + lane) * 8);
            }
#pragma unroll
            for (int t = 0; t < 8; t++)
#pragma unroll
                for (int m = 0; m < 2; m++)
                    acc[m][t] = __builtin_amdgcn_mfma_f32_16x16x32_bf16(av[m], bv[t], acc[m][t], 0, 0, 0);
        }
    }

    // ---- epilogue: C/D layout col=lane&15, row=ql*4+r ----
#pragma unroll
    for (int t = 0; t < 8; t++) {
        int colg = wc * 128 + t * 16 + ml;
        float b = bias[colg];
#pragma unroll
        for (int m = 0; m < 2; m++) {
            int rbase = row0 + (wr * 2 + m) * 16 + ql * 4;
#pragma unroll
            for (int r = 0; r < 4; r++) {
                int row = rbase + r;
                if (row >= M) continue;
                float v = acc[m][t][r] + b;
                if (RELU) v = fmaxf(v, 0.f);
                if (OUT_BF16) outB[(size_t)row * HDIM + colg] = f2bf(v);
                else          outF[(size_t)row * HDIM + colg] = v;
            }
        }
    }
}

// ---------------- host ----------------

extern "C" void kernel_launch(void* const* d_in, const int* in_sizes, int n_in,
                              void* d_out, int out_size, void* d_ws, size_t ws_size,
                              hipStream_t stream) {
    const float* x_user = (const float*)d_in[0];
    const float* x_item = (const float*)d_in[1];
    const int* eui_src = (const int*)d_in[2];
    const int* eui_dst = (const int*)d_in[3];
    const int* eiu_src = (const int*)d_in[4];
    const int* eiu_dst = (const int*)d_in[5];
    const float* W1l_ui = (const float*)d_in[6];
    const float* b1_ui  = (const float*)d_in[7];
    const float* W1r_ui = (const float*)d_in[8];
    const float* W1l_iu = (const float*)d_in[9];
    const float* b1_iu  = (const float*)d_in[10];
    const float* W1r_iu = (const float*)d_in[11];
    const float* W2l_ui = (const float*)d_in[12];
    const float* b2_ui  = (const float*)d_in[13];
    const float* W2r_ui = (const float*)d_in[14];
    const float* W2l_iu = (const float*)d_in[15];
    const float* b2_iu  = (const float*)d_in[16];
    const float* W2r_iu = (const float*)d_in[17];

    const int DU = 128, DI = 64;
    const int NU = in_sizes[0] / DU;   // 100000
    const int NI = in_sizes[1] / DI;   // 50000
    const int E  = in_sizes[2];        // 1600000

    char* base = (char*)d_ws;
    size_t off = 0;
    auto carve = [&](size_t bytes) -> char* {
        char* p = base + off;
        off += (bytes + 255) & ~(size_t)255;
        return p;
    };
    int* cnt_i  = (int*)carve((size_t)NI * 4);
    int* cnt_u  = (int*)carve((size_t)NU * 4);
    int* rp_i   = (int*)carve((size_t)(NI + 1) * 4);
    int* rp_u   = (int*)carve((size_t)(NU + 1) * 4);
    int* col_ui = (int*)carve((size_t)E * 4);
    int* col_iu = (int*)carve((size_t)E * 4);
    int* bsum   = (int*)carve(1024 * 4);
    int* boff   = (int*)carve(1024 * 4);
    u16* W1l_ui_b = (u16*)carve((size_t)HDIM * DU * 2);
    u16* W1r_ui_b = (u16*)carve((size_t)HDIM * DI * 2);
    u16* W1l_iu_b = (u16*)carve((size_t)HDIM * DI * 2);
    u16* W1r_iu_b = (u16*)carve((size_t)HDIM * DU * 2);
    u16* W2l_ui_b = (u16*)carve((size_t)HDIM * HDIM * 2);
    u16* W2r_ui_b = (u16*)carve((size_t)HDIM * HDIM * 2);
    u16* W2l_iu_b = (u16*)carve((size_t)HDIM * HDIM * 2);
    u16* W2r_iu_b = (u16*)carve((size_t)HDIM * HDIM * 2);
    char* slot1 = carve((size_t)NU * DU * 2);          // x_user_b, later B_i
    u16* x_user_b = (u16*)slot1;
    u16* B_i      = (u16*)slot1;
    char* slotB = carve((size_t)NU * HDIM * 2);        // x_item_b+A_i+A_u, later B_u
    u16* x_item_b = (u16*)slotB;
    u16* A_i      = (u16*)(slotB + (size_t)NI * DI * 2);
    u16* A_u      = (u16*)(slotB + (size_t)NI * DI * 2 + (size_t)NI * DU * 2);
    u16* B_u      = (u16*)slotB;
    u16* h_item_b = (u16*)carve((size_t)NI * HDIM * 2);
    u16* h_user_b = (u16*)carve((size_t)NU * HDIM * 2);

    float* out_user = (float*)d_out;
    float* out_item = (float*)d_out + (size_t)NU * HDIM;

    // ---- CSR build ----
    hipMemsetAsync(cnt_i, 0, (size_t)NI * 4, stream);
    hipMemsetAsync(cnt_u, 0, (size_t)NU * 4, stream);
    int egrid = (E + 255) / 256;
    hist_kernel<<<egrid, 256, 0, stream>>>(eui_dst, E, cnt_i);
    hist_kernel<<<egrid, 256, 0, stream>>>(eiu_dst, E, cnt_u);
    int Bi = (NI + 1023) / 1024, Bu = (NU + 1023) / 1024;
    block_reduce_kernel<<<Bi, 256, 0, stream>>>(cnt_i, NI, bsum);
    scan_sums_kernel<<<1, 64, 0, stream>>>(bsum, boff, Bi);
    block_scan_write_kernel<<<Bi, 1024, 0, stream>>>(cnt_i, NI, boff, rp_i, cnt_i, E);
    fill_kernel<<<egrid, 256, 0, stream>>>(eui_src, eui_dst, E, cnt_i, col_ui);
    block_reduce_kernel<<<Bu, 256, 0, stream>>>(cnt_u, NU, bsum);
    scan_sums_kernel<<<1, 64, 0, stream>>>(bsum, boff, Bu);
    block_scan_write_kernel<<<Bu, 1024, 0, stream>>>(cnt_u, NU, boff, rp_u, cnt_u, E);
    fill_kernel<<<egrid, 256, 0, stream>>>(eiu_src, eiu_dst, E, cnt_u, col_iu);

    // ---- converts ----
    auto conv = [&](const float* in, u16* outp, size_t n) {
        int n4 = (int)(n / 4);
        f32_to_bf16_kernel<<<(n4 + 255) / 256, 256, 0, stream>>>(in, outp, n4);
    };
    conv(x_user, x_user_b, (size_t)NU * DU);
    conv(x_item, x_item_b, (size_t)NI * DI);
    conv(W1l_ui, W1l_ui_b, (size_t)HDIM * DU);
    conv(W1r_ui, W1r_ui_b, (size_t)HDIM * DI);
    conv(W1l_iu, W1l_iu_b, (size_t)HDIM * DI);
    conv(W1r_iu, W1r_iu_b, (size_t)HDIM * DU);
    conv(W2l_ui, W2l_ui_b, (size_t)HDIM * HDIM);
    conv(W2r_ui, W2r_ui_b, (size_t)HDIM * HDIM);
    conv(W2l_iu, W2l_iu_b, (size_t)HDIM * HDIM);
    conv(W2r_iu, W2r_iu_b, (size_t)HDIM * HDIM);

    // ---- layer 1 ----
    agg_mean<128><<<(NI + 3) / 4, 256, 0, stream>>>(x_user_b, rp_i, col_ui, A_i, NI);
    agg_mean<64> <<<(NU + 3) / 4, 256, 0, stream>>>(x_item_b, rp_u, col_iu, A_u, NU);
    gemm2<128, 64, true, true><<<(NI + 63) / 64, 256, 0, stream>>>(
        A_i, x_item_b, W1l_ui_b, W1r_ui_b, b1_ui, nullptr, h_item_b, NI);
    gemm2<64, 128, true, true><<<(NU + 63) / 64, 256, 0, stream>>>(
        A_u, x_user_b, W1l_iu_b, W1r_iu_b, b1_iu, nullptr, h_user_b, NU);

    // ---- layer 2 ----
    agg_mean_256<<<(NI + 7) / 8, 256, 0, stream>>>(h_user_b, rp_i, col_ui, B_i, NI);
    agg_mean_256<<<(NU + 7) / 8, 256, 0, stream>>>(h_item_b, rp_u, col_iu, B_u, NU);
    gemm2<256, 256, false, false><<<(NI + 63) / 64, 256, 0, stream>>>(
        B_i, h_item_b, W2l_ui_b, W2r_ui_b, b2_ui, out_item, nullptr, NI);
    gemm2<256, 256, false, false><<<(NU + 63) / 64, 256, 0, stream>>>(
        B_u, h_user_b, W2l_iu_b, W2r_iu_b, b2_iu, out_user, nullptr, NU);
}